// Round 1
// baseline (248.559 us; speedup 1.0000x reference)
//
#include <hip/hip_runtime.h>
#include <hip/hip_bf16.h>

// Problem constants (from reference): B,L,M,D,K,STRIDE = 32,32768,32,128,16,8
#define Bn 32
#define Ln 32768
#define Mn 32
#define Dn 128
#define Pn 4095            // (L - K)/STRIDE + 1
#define KKn 512            // M*K  (GEMM reduction dim)

typedef short  bf16x8 __attribute__((ext_vector_type(8)));  // 8 bf16 = 4 VGPRs
typedef float  f32x4  __attribute__((ext_vector_type(4)));

union BU { bf16x8 v; unsigned short u[8]; };

static __device__ __forceinline__ unsigned short f2bf(float f) {
  __hip_bfloat16 h = __float2bfloat16(f);
  return *reinterpret_cast<unsigned short*>(&h);
}

// ---------------------------------------------------------------------------
// Prep: conv_w (D,M,K) fp32 -> fragment-ready swizzled bf16 in d_ws.
// GEMM K-index kk = k*32 + m  (window row k, channel m) so that the A-operand
// (x window) is contiguous. B-fragment for lane: d = lane&15,
// kk = t*32 + quad*8 + j  -> store at [( (kk>>3)*128 + d )*8 + (kk&7)]
// so each fragment is ONE 16-B aligned load of 8 contiguous bf16.
// ---------------------------------------------------------------------------
__global__ __launch_bounds__(256) void prep_w_kernel(const float* __restrict__ w,
                                                     unsigned short* __restrict__ wswz) {
  int idx = blockIdx.x * 256 + threadIdx.x;   // 0..65535 — coalesced writes
  int j = idx & 7;
  int d = (idx >> 3) & 127;
  int g = idx >> 10;          // kk>>3, 0..63
  int kk = g * 8 + j;         // 0..511
  int k = kk >> 5;            // window row   (K index, 0..15)
  int m = kk & 31;            // channel      (M index)
  wswz[idx] = f2bf(w[(d << 9) + (m << 4) + k]);   // w[d][m][k]
}

// ---------------------------------------------------------------------------
// Main: per block, 64 patches x 128 d.  4 waves: wave w owns d in [w*32,w*32+32).
// x slab (520 rows x 32 ch) staged to LDS as bf16 with XOR granule swizzle to
// kill the 16-way bank conflict on A-fragment ds_read_b128 (p-stride 512 B).
// ---------------------------------------------------------------------------
__global__ __launch_bounds__(256, 4) void gemm_pe_kernel(
    const float* __restrict__ x,          // (B, L, M) fp32
    const float* __restrict__ ts,         // (B, L)    fp32, sorted along L
    const unsigned short* __restrict__ wswz,
    const float* __restrict__ bias,       // (D,)
    float* __restrict__ out) {            // (B, P, D) fp32

  __shared__ unsigned short xs[2080 * 8]; // 16640 bf16 = 33,280 B

  const int b   = blockIdx.y;
  const int pt0 = blockIdx.x;             // patch-tile id, 0..63 (64 patches each)
  const int tid = threadIdx.x;

  // ---- stage x slab -> LDS bf16 (xor-swizzled 16-B granules) ----
  const float* xsrc = x + (size_t)b * Ln * Mn + (size_t)pt0 * 512 * Mn;
  const int r0 = pt0 * 512;               // first global row of slab
  for (int g = tid; g < 2080; g += 256) {
    int s = g * 8;                        // slab element offset (all 8 in one row)
    int row = r0 + (s >> 5);
    float4 f0, f1;
    if (row < Ln) {
      f0 = *reinterpret_cast<const float4*>(xsrc + s);
      f1 = *reinterpret_cast<const float4*>(xsrc + s + 4);
    } else {
      f0 = make_float4(0.f, 0.f, 0.f, 0.f);
      f1 = f0;                            // rows past L only feed masked patch 4095
    }
    BU bu;
    bu.u[0] = f2bf(f0.x); bu.u[1] = f2bf(f0.y); bu.u[2] = f2bf(f0.z); bu.u[3] = f2bf(f0.w);
    bu.u[4] = f2bf(f1.x); bu.u[5] = f2bf(f1.y); bu.u[6] = f2bf(f1.z); bu.u[7] = f2bf(f1.w);
    int phys = (g & ~7) | ((g & 7) ^ ((g >> 5) & 7));   // xor swizzle, 16B granules
    *reinterpret_cast<bf16x8*>(&xs[phys * 8]) = bu.v;
  }
  __syncthreads();

  const int lane = tid & 63;
  const int wv   = tid >> 6;              // 0..3 -> d block
  const int mrow = lane & 15;             // A row (patch) / B col (d) / D col (d)
  const int quad = lane >> 4;             // 0..3

  f32x4 acc[4][2] = {};                   // 4 patch-tiles x 2 d-tiles

  #pragma unroll
  for (int t = 0; t < 16; ++t) {          // K-steps of 32 over KK=512
    bf16x8 afrag[4];
    #pragma unroll
    for (int pt = 0; pt < 4; ++pt) {
      int p_loc = pt * 16 + mrow;                       // 0..63
      int g = p_loc * 32 + t * 4 + quad;                // logical granule
      int phys = (g & ~7) | ((g & 7) ^ ((g >> 5) & 7));
      afrag[pt] = *reinterpret_cast<const bf16x8*>(&xs[phys * 8]);
    }
    bf16x8 bfrag[2];
    #pragma unroll
    for (int dt = 0; dt < 2; ++dt) {
      int d = wv * 32 + dt * 16 + mrow;
      bfrag[dt] = *reinterpret_cast<const bf16x8*>(
          &wswz[((((t << 2) + quad) << 7) + d) << 3]);  // ((t*4+quad)*128+d)*8
    }
    #pragma unroll
    for (int pt = 0; pt < 4; ++pt)
      #pragma unroll
      for (int dt = 0; dt < 2; ++dt)
        acc[pt][dt] = __builtin_amdgcn_mfma_f32_16x16x32_bf16(
            afrag[pt], bfrag[dt], acc[pt][dt], 0, 0, 0);
  }

  // ---- epilogue: + bias + positional encoding; D-layout col=lane&15,
  //      row = quad*4 + reg  [m89/m91-verified mapping] ----
  // div_term[i] = exp(-ln(10000)/64 * i), i = d>>1;  pe = sin(ang + (d&1)*pi/2)
  const float NEG_C = -0.14391156831212810f;            // -ln(10000)/64
  float div[2], phs;
  {
    int d0 = wv * 32 + mrow;
    div[0] = __expf(NEG_C * (float)(d0 >> 1));
    div[1] = __expf(NEG_C * (float)((d0 + 16) >> 1));
    phs = (d0 & 1) ? 1.5707963267948966f : 0.0f;        // parity same for both dt
  }
  const float* tsb = ts + (size_t)b * Ln;
  #pragma unroll
  for (int pt = 0; pt < 4; ++pt) {
    #pragma unroll
    for (int reg = 0; reg < 4; ++reg) {
      int p = pt0 * 64 + pt * 16 + quad * 4 + reg;
      if (p < Pn) {
        float med = tsb[p * 8 + 7];                     // ts sorted -> median of 16-window
        size_t ob = ((size_t)b * Pn + p) * Dn;
        #pragma unroll
        for (int dt = 0; dt < 2; ++dt) {
          int d = wv * 32 + dt * 16 + mrow;
          float pe = sinf(med * div[dt] + phs);
          out[ob + d] = acc[pt][dt][reg] + bias[d] + pe;
        }
      }
    }
  }
}

extern "C" void kernel_launch(void* const* d_in, const int* in_sizes, int n_in,
                              void* d_out, int out_size, void* d_ws, size_t ws_size,
                              hipStream_t stream) {
  const float* x      = (const float*)d_in[0];   // (32, 32768, 32)
  const float* ts     = (const float*)d_in[1];   // (32, 32768)
  const float* conv_w = (const float*)d_in[2];   // (128, 32, 16)
  const float* conv_b = (const float*)d_in[3];   // (128,)
  float* out = (float*)d_out;
  unsigned short* wswz = (unsigned short*)d_ws;  // 512*128 bf16 = 128 KiB

  prep_w_kernel<<<256, 256, 0, stream>>>(conv_w, wswz);
  gemm_pe_kernel<<<dim3(64, Bn), 256, 0, stream>>>(x, ts, wswz, conv_b, out);
}

// Round 2
// 225.813 us; speedup vs baseline: 1.1007x; 1.1007x over previous
//
#include <hip/hip_runtime.h>
#include <hip/hip_bf16.h>

// Problem constants: B,L,M,D,K,STRIDE = 32,32768,32,128,16,8
#define Bn 32
#define Ln 32768
#define Mn 32
#define Dn 128
#define Pn 4095            // (L - K)/STRIDE + 1
#define KKn 512            // M*K  (GEMM reduction dim)

typedef short  bf16x8 __attribute__((ext_vector_type(8)));  // 8 bf16 = 4 VGPRs
typedef float  f32x4  __attribute__((ext_vector_type(4)));

union BU { bf16x8 v; unsigned short u[8]; };

static __device__ __forceinline__ unsigned short f2bf(float f) {
  __hip_bfloat16 h = __float2bfloat16(f);
  return *reinterpret_cast<unsigned short*>(&h);
}

static __device__ __forceinline__ int swz(int g) {
  // xor swizzle on 16-B granules: kills the 512-B p-stride bank conflict
  return (g & ~7) | ((g & 7) ^ ((g >> 5) & 7));
}

// ---------------------------------------------------------------------------
// Prep: conv_w (D,M,K) fp32 -> fragment-ready swizzled bf16 in d_ws.
// kk = k*32 + m; B-frag lane d=lane&15, kk=t*32+quad*8+j
//   -> wswz[((kk>>3)*128 + d)*8 + (kk&7)]  (one 16-B load per fragment)
// ---------------------------------------------------------------------------
__global__ __launch_bounds__(256) void prep_w_kernel(const float* __restrict__ w,
                                                     unsigned short* __restrict__ wswz) {
  int idx = blockIdx.x * 256 + threadIdx.x;   // 0..65535
  int j = idx & 7;
  int d = (idx >> 3) & 127;
  int g = idx >> 10;
  int kk = g * 8 + j;
  int k = kk >> 5;
  int m = kk & 31;
  wswz[idx] = f2bf(w[(d << 9) + (m << 4) + k]);   // w[d][m][k]
}

// ---------------------------------------------------------------------------
// Main: 64 patches x 128 d per block. 4 waves; wave w owns d in [w*32,w*32+32).
// ---------------------------------------------------------------------------
__global__ __launch_bounds__(256, 4) void gemm_pe_kernel(
    const float* __restrict__ x,          // (B, L, M) fp32
    const float* __restrict__ ts,         // (B, L)    fp32, sorted along L
    const unsigned short* __restrict__ wswz,
    const float* __restrict__ bias,       // (D,)
    float* __restrict__ out) {            // (B, P, D) fp32

  __shared__ unsigned short xs[2080 * 8]; // 33,280 B
  __shared__ float tsl[64];               // medians for this block's 64 patches

  const int b   = blockIdx.y;
  const int pt0 = blockIdx.x;             // patch-tile id, 0..63
  const int tid = threadIdx.x;
  const int lane = tid & 63;
  const int wv   = tid >> 6;
  const int mrow = lane & 15;
  const int quad = lane >> 4;

  // hoist epilogue scalars early (hide their latency under staging)
  const int d0 = wv * 32 + mrow;
  const float NEG_C = -0.14391156831212810f;            // -ln(10000)/64
  const float div0 = __expf(NEG_C * (float)(d0 >> 1));
  const float div1 = __expf(NEG_C * (float)((d0 + 16) >> 1));
  const float phs  = (d0 & 1) ? 1.5707963267948966f : 0.0f;
  const float bias0 = bias[d0];
  const float bias1 = bias[d0 + 16];

  // ---- stage x slab -> LDS bf16 (branch-free main body, batched loads) ----
  const float* xsrc = x + (size_t)b * Ln * Mn + (size_t)pt0 * 512 * Mn;
  const int r0 = pt0 * 512;

  float4 f[8][2];
  #pragma unroll
  for (int i = 0; i < 8; ++i) {           // granules 0..2047: in-bounds for ALL blocks
    int g = i * 256 + tid;
    const float4* src = reinterpret_cast<const float4*>(xsrc) + (size_t)g * 2;
    f[i][0] = src[0];
    f[i][1] = src[1];
  }
  // ts medians for this block's patches (sorted ts -> median of 16-window = idx 7)
  if (tid >= 64 && tid < 128) {
    int pl = tid - 64;
    tsl[pl] = ts[(size_t)b * Ln + r0 + pl * 8 + 7];
  }
  #pragma unroll
  for (int i = 0; i < 8; ++i) {
    int g = i * 256 + tid;
    BU bu;
    bu.u[0] = f2bf(f[i][0].x); bu.u[1] = f2bf(f[i][0].y);
    bu.u[2] = f2bf(f[i][0].z); bu.u[3] = f2bf(f[i][0].w);
    bu.u[4] = f2bf(f[i][1].x); bu.u[5] = f2bf(f[i][1].y);
    bu.u[6] = f2bf(f[i][1].z); bu.u[7] = f2bf(f[i][1].w);
    *reinterpret_cast<bf16x8*>(&xs[swz(g) * 8]) = bu.v;
  }
  // tail granules 2048..2079 (slab rows 512..519): OOB only for pt0==63
  if (tid < 32) {
    int g = 2048 + tid;
    BU bu;
    if (pt0 < 63) {
      const float4* src = reinterpret_cast<const float4*>(xsrc) + (size_t)g * 2;
      float4 t0 = src[0], t1 = src[1];
      bu.u[0] = f2bf(t0.x); bu.u[1] = f2bf(t0.y); bu.u[2] = f2bf(t0.z); bu.u[3] = f2bf(t0.w);
      bu.u[4] = f2bf(t1.x); bu.u[5] = f2bf(t1.y); bu.u[6] = f2bf(t1.z); bu.u[7] = f2bf(t1.w);
    } else {
      bu.v = (bf16x8)0;
    }
    *reinterpret_cast<bf16x8*>(&xs[swz(g) * 8]) = bu.v;
  }
  __syncthreads();

  // ---- K-loop: 16 steps of K=32, register-ring prefetch ----
  int agbase[4];
  #pragma unroll
  for (int pt = 0; pt < 4; ++pt) agbase[pt] = (pt * 16 + mrow) * 32 + quad;
  const unsigned short* bbase = wswz + (((quad << 7) + (wv << 5) + mrow) << 3);
  // A frag at t: granule agbase[pt] + t*4 ; B frag (dt,t): bbase + dt*128 + t*4096

  f32x4 acc[4][2] = {};

  bf16x8 a_cur[4];
  #pragma unroll
  for (int pt = 0; pt < 4; ++pt)
    a_cur[pt] = *reinterpret_cast<const bf16x8*>(&xs[swz(agbase[pt]) * 8]);

  bf16x8 bp[3][2];                        // B prefetch ring, depth 3
  #pragma unroll
  for (int j = 0; j < 3; ++j) {
    bp[j][0] = *reinterpret_cast<const bf16x8*>(bbase + j * 4096);
    bp[j][1] = *reinterpret_cast<const bf16x8*>(bbase + 128 + j * 4096);
  }

  #pragma unroll
  for (int t = 0; t < 16; ++t) {
    const int cur = t % 3;
    bf16x8 a_nxt[4];
    if (t < 15) {
      #pragma unroll
      for (int pt = 0; pt < 4; ++pt)
        a_nxt[pt] = *reinterpret_cast<const bf16x8*>(&xs[swz(agbase[pt] + (t + 1) * 4) * 8]);
    }
    bf16x8 bc0 = bp[cur][0], bc1 = bp[cur][1];
    if (t < 13) {
      bp[cur][0] = *reinterpret_cast<const bf16x8*>(bbase + (t + 3) * 4096);
      bp[cur][1] = *reinterpret_cast<const bf16x8*>(bbase + 128 + (t + 3) * 4096);
    }
    #pragma unroll
    for (int pt = 0; pt < 4; ++pt) {
      acc[pt][0] = __builtin_amdgcn_mfma_f32_16x16x32_bf16(a_cur[pt], bc0, acc[pt][0], 0, 0, 0);
      acc[pt][1] = __builtin_amdgcn_mfma_f32_16x16x32_bf16(a_cur[pt], bc1, acc[pt][1], 0, 0, 0);
    }
    if (t < 15) {
      #pragma unroll
      for (int pt = 0; pt < 4; ++pt) a_cur[pt] = a_nxt[pt];
    }
  }

  // ---- epilogue: + bias + PE.  C/D layout: col=lane&15, row=quad*4+reg ----
  #pragma unroll
  for (int pt = 0; pt < 4; ++pt) {
    const int plbase = pt * 16 + quad * 4;
    f32x4 med4 = *reinterpret_cast<const f32x4*>(&tsl[plbase]);
    const int pbase = pt0 * 64 + plbase;
    float* obase = out + ((size_t)b * Pn + pbase) * Dn + d0;
    #pragma unroll
    for (int reg = 0; reg < 4; ++reg) {
      if (pbase + reg < Pn) {
        float m = med4[reg];
        float pe0 = __sinf(m * div0 + phs);
        float pe1 = __sinf(m * div1 + phs);
        obase[reg * Dn]      = acc[pt][0][reg] + bias0 + pe0;
        obase[reg * Dn + 16] = acc[pt][1][reg] + bias1 + pe1;
      }
    }
  }
}

extern "C" void kernel_launch(void* const* d_in, const int* in_sizes, int n_in,
                              void* d_out, int out_size, void* d_ws, size_t ws_size,
                              hipStream_t stream) {
  const float* x      = (const float*)d_in[0];   // (32, 32768, 32)
  const float* ts     = (const float*)d_in[1];   // (32, 32768)
  const float* conv_w = (const float*)d_in[2];   // (128, 32, 16)
  const float* conv_b = (const float*)d_in[3];   // (128,)
  float* out = (float*)d_out;
  unsigned short* wswz = (unsigned short*)d_ws;  // 512*128 bf16 = 128 KiB

  prep_w_kernel<<<256, 256, 0, stream>>>(conv_w, wswz);
  gemm_pe_kernel<<<dim3(64, Bn), 256, 0, stream>>>(x, ts, wswz, conv_b, out);
}

// Round 3
// 223.734 us; speedup vs baseline: 1.1110x; 1.0093x over previous
//
#include <hip/hip_runtime.h>
#include <hip/hip_bf16.h>

// Problem constants: B,L,M,D,K,STRIDE = 32,32768,32,128,16,8
#define Bn 32
#define Ln 32768
#define Mn 32
#define Dn 128
#define Pn 4095            // (L - K)/STRIDE + 1
#define KKn 512            // M*K  (GEMM reduction dim)

typedef short  bf16x8 __attribute__((ext_vector_type(8)));  // 8 bf16 = 4 VGPRs
typedef float  f32x4  __attribute__((ext_vector_type(4)));

union BU { bf16x8 v; unsigned short u[8]; };

static __device__ __forceinline__ unsigned short f2bf(float f) {
  __hip_bfloat16 h = __float2bfloat16(f);
  return *reinterpret_cast<unsigned short*>(&h);
}

static __device__ __forceinline__ int swz(int g) {
  // xor swizzle on 16-B granules: kills the 512-B p-stride bank conflict
  return (g & ~7) | ((g & 7) ^ ((g >> 5) & 7));
}

// ---------------------------------------------------------------------------
// Prep: conv_w (D,M,K) fp32 -> fragment-ready swizzled bf16 in d_ws.
// kk = k*32 + m; B-frag lane d=lane&15, kk=t*32+quad*8+j
//   -> wswz[((kk>>3)*128 + d)*8 + (kk&7)]  (one 16-B load per fragment)
// ---------------------------------------------------------------------------
__global__ __launch_bounds__(256) void prep_w_kernel(const float* __restrict__ w,
                                                     unsigned short* __restrict__ wswz) {
  int idx = blockIdx.x * 256 + threadIdx.x;   // 0..65535
  int j = idx & 7;
  int d = (idx >> 3) & 127;
  int g = idx >> 10;
  int kk = g * 8 + j;
  int k = kk >> 5;
  int m = kk & 31;
  wswz[idx] = f2bf(w[(d << 9) + (m << 4) + k]);   // w[d][m][k]
}

// ---------------------------------------------------------------------------
// Main: 64 patches x 128 d per block. 4 waves; wave w owns d in [w*32,w*32+32).
// ---------------------------------------------------------------------------
__global__ __launch_bounds__(256, 4) void gemm_pe_kernel(
    const float* __restrict__ x,          // (B, L, M) fp32
    const float* __restrict__ ts,         // (B, L)    fp32, sorted along L
    const unsigned short* __restrict__ wswz,
    const float* __restrict__ bias,       // (D,)
    float* __restrict__ out) {            // (B, P, D) fp32

  __shared__ unsigned short xs[2080 * 8]; // 33,280 B
  __shared__ float tsl[64];               // medians for this block's 64 patches

  const int b   = blockIdx.y;
  const int pt0 = blockIdx.x;             // patch-tile id, 0..63
  const int tid = threadIdx.x;
  const int lane = tid & 63;
  const int wv   = tid >> 6;
  const int mrow = lane & 15;
  const int quad = lane >> 4;

  const float* xsrc = x + (size_t)b * Ln * Mn + (size_t)pt0 * 512 * Mn;
  const int r0 = pt0 * 512;

  // ---------------- issue ALL independent global loads back-to-back --------
  // x slab: 16 dwordx4 per thread (granules 0..2047 in-bounds for every block)
  float4 f[8][2];
  #pragma unroll
  for (int i = 0; i < 8; ++i) {
    int g = i * 256 + tid;
    const float4* src = reinterpret_cast<const float4*>(xsrc) + (size_t)g * 2;
    f[i][0] = src[0];
    f[i][1] = src[1];
  }
  // tail granules 2048..2079 (slab rows 512..519): OOB only for pt0==63
  float4 t0 = make_float4(0.f, 0.f, 0.f, 0.f), t1 = t0;
  if (tid < 32 && pt0 < 63) {
    const float4* src = reinterpret_cast<const float4*>(xsrc) + (size_t)(2048 + tid) * 2;
    t0 = src[0];
    t1 = src[1];
  }
  // ts medians (sorted ts -> median of even 16-window = element 7)
  float tsv = 0.f;
  if (tid >= 64 && tid < 128)
    tsv = ts[(size_t)b * Ln + r0 + (tid - 64) * 8 + 7];
  // initial B-frag ring (global, L2-resident) — newest in vmcnt order, so the
  // convert loop's waitcnts leave these in flight
  const unsigned short* bbase = wswz + (((quad << 7) + (wv << 5) + mrow) << 3);
  bf16x8 bp[3][2];
  #pragma unroll
  for (int j = 0; j < 3; ++j) {
    bp[j][0] = *reinterpret_cast<const bf16x8*>(bbase + j * 4096);
    bp[j][1] = *reinterpret_cast<const bf16x8*>(bbase + 128 + j * 4096);
  }
  // epilogue scalars (VALU, free under load shadow)
  const int d0 = wv * 32 + mrow;
  const float NEG_C = -0.14391156831212810f;            // -ln(10000)/64
  const float div0 = __expf(NEG_C * (float)(d0 >> 1));
  const float div1 = __expf(NEG_C * (float)((d0 + 16) >> 1));
  const float phs  = (d0 & 1) ? 1.5707963267948966f : 0.0f;
  const float bias0 = bias[d0];
  const float bias1 = bias[d0 + 16];

  __builtin_amdgcn_sched_barrier(0);   // keep every load above issued first

  // ---------------- drain in issue order: convert + ds_write ---------------
  #pragma unroll
  for (int i = 0; i < 8; ++i) {
    int g = i * 256 + tid;
    BU bu;
    bu.u[0] = f2bf(f[i][0].x); bu.u[1] = f2bf(f[i][0].y);
    bu.u[2] = f2bf(f[i][0].z); bu.u[3] = f2bf(f[i][0].w);
    bu.u[4] = f2bf(f[i][1].x); bu.u[5] = f2bf(f[i][1].y);
    bu.u[6] = f2bf(f[i][1].z); bu.u[7] = f2bf(f[i][1].w);
    *reinterpret_cast<bf16x8*>(&xs[swz(g) * 8]) = bu.v;
  }
  if (tid < 32) {
    BU bu;
    bu.u[0] = f2bf(t0.x); bu.u[1] = f2bf(t0.y); bu.u[2] = f2bf(t0.z); bu.u[3] = f2bf(t0.w);
    bu.u[4] = f2bf(t1.x); bu.u[5] = f2bf(t1.y); bu.u[6] = f2bf(t1.z); bu.u[7] = f2bf(t1.w);
    *reinterpret_cast<bf16x8*>(&xs[swz(2048 + tid) * 8]) = bu.v;
  }
  if (tid >= 64 && tid < 128) tsl[tid - 64] = tsv;
  __syncthreads();

  // ---------------- K-loop: 16 steps of K=32, register-ring prefetch -------
  int agbase[4];
  #pragma unroll
  for (int pt = 0; pt < 4; ++pt) agbase[pt] = (pt * 16 + mrow) * 32 + quad;

  f32x4 acc[4][2] = {};

  bf16x8 a_cur[4];
  #pragma unroll
  for (int pt = 0; pt < 4; ++pt)
    a_cur[pt] = *reinterpret_cast<const bf16x8*>(&xs[swz(agbase[pt]) * 8]);

  #pragma unroll
  for (int t = 0; t < 16; ++t) {
    const int cur = t % 3;
    bf16x8 a_nxt[4];
    if (t < 15) {
      #pragma unroll
      for (int pt = 0; pt < 4; ++pt)
        a_nxt[pt] = *reinterpret_cast<const bf16x8*>(&xs[swz(agbase[pt] + (t + 1) * 4) * 8]);
    }
    bf16x8 bc0 = bp[cur][0], bc1 = bp[cur][1];
    if (t < 13) {
      bp[cur][0] = *reinterpret_cast<const bf16x8*>(bbase + (t + 3) * 4096);
      bp[cur][1] = *reinterpret_cast<const bf16x8*>(bbase + 128 + (t + 3) * 4096);
    }
    #pragma unroll
    for (int pt = 0; pt < 4; ++pt) {
      acc[pt][0] = __builtin_amdgcn_mfma_f32_16x16x32_bf16(a_cur[pt], bc0, acc[pt][0], 0, 0, 0);
      acc[pt][1] = __builtin_amdgcn_mfma_f32_16x16x32_bf16(a_cur[pt], bc1, acc[pt][1], 0, 0, 0);
    }
    if (t < 15) {
      #pragma unroll
      for (int pt = 0; pt < 4; ++pt) a_cur[pt] = a_nxt[pt];
    }
  }

  // ---------------- epilogue: + bias + PE.  C/D: col=lane&15, row=quad*4+reg
  #pragma unroll
  for (int pt = 0; pt < 4; ++pt) {
    const int plbase = pt * 16 + quad * 4;
    f32x4 med4 = *reinterpret_cast<const f32x4*>(&tsl[plbase]);
    const int pbase = pt0 * 64 + plbase;
    float* obase = out + ((size_t)b * Pn + pbase) * Dn + d0;
    #pragma unroll
    for (int reg = 0; reg < 4; ++reg) {
      if (pbase + reg < Pn) {
        float m = med4[reg];
        float pe0 = __sinf(m * div0 + phs);
        float pe1 = __sinf(m * div1 + phs);
        obase[reg * Dn]      = acc[pt][0][reg] + bias0 + pe0;
        obase[reg * Dn + 16] = acc[pt][1][reg] + bias1 + pe1;
      }
    }
  }
}

extern "C" void kernel_launch(void* const* d_in, const int* in_sizes, int n_in,
                              void* d_out, int out_size, void* d_ws, size_t ws_size,
                              hipStream_t stream) {
  const float* x      = (const float*)d_in[0];   // (32, 32768, 32)
  const float* ts     = (const float*)d_in[1];   // (32, 32768)
  const float* conv_w = (const float*)d_in[2];   // (128, 32, 16)
  const float* conv_b = (const float*)d_in[3];   // (128,)
  float* out = (float*)d_out;
  unsigned short* wswz = (unsigned short*)d_ws;  // 512*128 bf16 = 128 KiB

  prep_w_kernel<<<256, 256, 0, stream>>>(conv_w, wswz);
  gemm_pe_kernel<<<dim3(64, Bn), 256, 0, stream>>>(x, ts, wswz, conv_b, out);
}